// Round 8
// baseline (26.044 us; speedup 1.0000x reference)
//
#include <hip/hip_runtime.h>
#include <math.h>

// ---------------------------------------------------------------------------
// N-pair Gaussian mixture log-likelihood, factorized form:
//   arg_ij(x) = g_i(x) + g_j(x) + c_ij,  g_i(x) = -0.5 x'prec_i x + x'rhs_i
//   pdf(x)    = u' E u,  u_i = exp(g_i(x)),  E_ij = exp(c_ij + 64 ln2)  [scaled]
//   out       = mean_n( log pdf_n ) + log z_last   (scale folded into Kconst)
// Main kernel: 2 points/thread packed as float2 -> v_pk_fma_f32, constants
// streamed from LDS as float4 broadcasts. No atomics -> deterministic.
// ---------------------------------------------------------------------------

#define LOG2E_F 1.4426950408889634f
#define LN2_F   0.6931471805599453f
#define LN2PI_F 1.8378770664093453f   // ln(2*pi)

// ws layout (float offsets). Staged region = [0,1024) = 256 float4.
#define WS_COEF 0      // 16 rows * 48: per d {lin_d, Q_dd..Q_d7} *log2e; 44 used
#define WS_ES   768    // 160: packed lower-tri E rows, each padded to 16B
#define WS_K    1024   // Kconst = log z_last - 64 ln2  (outside staged region)
#define WS_PART 1088   // per-block partial sums

typedef float f2 __attribute__((ext_vector_type(2)));

// Padded-packed E row offsets (floats)
__device__ const int EOFF_D[16] = {0,4,8,12,16,24,32,40,48,60,72,84,96,112,128,144};

__device__ __forceinline__ float fexp2(float x) {
#if __has_builtin(__builtin_amdgcn_exp2f)
  return __builtin_amdgcn_exp2f(x);
#else
  return exp2f(x);
#endif
}
__device__ __forceinline__ float flog2(float x) {
#if __has_builtin(__builtin_amdgcn_logf)
  return __builtin_amdgcn_logf(x);
#else
  return log2f(x);
#endif
}
__device__ __forceinline__ f2 vfma(float c, f2 x, f2 a) {   // pk_fma candidate
  return __builtin_elementwise_fma((f2){c, c}, x, a);
}

// Cholesky: A = C C^T (lower). Only lower triangle of A read. Fully unrolled.
__device__ __forceinline__ void chol8(const float (*A)[8], float (*C)[8]) {
  #pragma unroll
  for (int d = 0; d < 8; ++d) {
    float s = A[d][d];
    #pragma unroll
    for (int m = 0; m < 8; ++m) if (m < d) s -= C[d][m] * C[d][m];
    float cd = sqrtf(s);
    C[d][d] = cd;
    float inv = 1.f / cd;
    #pragma unroll
    for (int e = 0; e < 8; ++e) if (e > d) {
      float t = A[e][d];
      #pragma unroll
      for (int m = 0; m < 8; ++m) if (m < d) t -= C[e][m] * C[d][m];
      C[e][d] = t * inv;
    }
  }
}

// ---------------------------------------------------------------------------
// Kernel A: all setup in one block (unchanged from round 7).
// ---------------------------------------------------------------------------
__global__ __launch_bounds__(256) void gm_setup(const float* __restrict__ mu,
                                                const float* __restrict__ L,
                                                const float* __restrict__ wts,
                                                float* __restrict__ ws) {
  __shared__ float sp[16][72];   // prec[64] + rhs[8] per component
  int tid = threadIdx.x;
  ws[768 + tid] = 0.f;           // zero [768,1024): E pads + tail
  if (tid < 16) {
    int k = tid;
    float Lt[8][8];
    #pragma unroll
    for (int d = 0; d < 8; ++d)
      #pragma unroll
      for (int e = 0; e < 8; ++e)
        Lt[d][e] = (e <= d) ? L[k * 64 + d * 8 + e] : 0.f;
    float A[8][8];
    #pragma unroll
    for (int d = 0; d < 8; ++d)
      #pragma unroll
      for (int e = 0; e <= d; ++e) {
        float s = (d == e) ? 1.f : 0.f;
        #pragma unroll
        for (int m = 0; m < 8; ++m) s += Lt[d][m] * Lt[e][m];
        A[d][e] = s;
        A[e][d] = s;
      }
    float C[8][8];
    chol8(A, C);
    float Ci[8][8];
    #pragma unroll
    for (int d = 0; d < 8; ++d) Ci[d][d] = 1.f / C[d][d];
    #pragma unroll
    for (int e = 0; e < 8; ++e)
      #pragma unroll
      for (int d = 0; d < 8; ++d) if (d > e) {
        float s = 0.f;
        #pragma unroll
        for (int m = 0; m < 8; ++m) if (m >= e && m < d) s += C[d][m] * Ci[m][e];
        Ci[d][e] = -s * Ci[d][d];
      }
    #pragma unroll
    for (int a = 0; a < 8; ++a)
      #pragma unroll
      for (int b = 0; b < 8; ++b) {
        float s = 0.f;
        #pragma unroll
        for (int m = 0; m < 8; ++m) if (m >= a && m >= b) s += Ci[m][a] * Ci[m][b];
        sp[k][a * 8 + b] = s;
      }
    #pragma unroll
    for (int d = 0; d < 8; ++d) {
      float s = 0.f;
      #pragma unroll
      for (int e = 0; e < 8; ++e) s += sp[k][d * 8 + e] * mu[k * 8 + e];
      sp[k][64 + d] = s;
    }
  }
  __syncthreads();

  int p = tid;
  int i = p >> 4, j = p & 15;
  const float* pi = sp[i];
  const float* pj = sp[j];
  float P[8][8], rp[8];
  #pragma unroll
  for (int d = 0; d < 8; ++d) {
    #pragma unroll
    for (int e = 0; e < 8; ++e) P[d][e] = pi[d * 8 + e] + pj[d * 8 + e];
    rp[d] = pi[64 + d] + pj[64 + d];
  }
  float U[8][8];
  chol8(P, U);
  float logdet = 0.f;
  #pragma unroll
  for (int d = 0; d < 8; ++d) logdet += logf(U[d][d]);
  logdet *= 2.f;
  float zf[8];
  #pragma unroll
  for (int d = 0; d < 8; ++d) {
    float s = rp[d];
    #pragma unroll
    for (int m = 0; m < 8; ++m) if (m < d) s -= U[d][m] * zf[m];
    zf[d] = s / U[d][d];
  }
  float y[8];
  #pragma unroll
  for (int dd = 7; dd >= 0; --dd) {
    float s = zf[dd];
    #pragma unroll
    for (int m = 0; m < 8; ++m) if (m > dd) s -= U[m][dd] * y[m];
    y[dd] = s / U[dd][dd];
  }
  float muPmu = 0.f;
  #pragma unroll
  for (int d = 0; d < 8; ++d) muPmu += rp[d] * y[d];
  float c = -0.5f * muPmu + 0.5f * logdet - 32.f * LN2PI_F
          + logf(wts[i]) + logf(wts[j]) + 64.f * LN2_F;
  float Ev = expf(c);
  if (j <= i)   // padded-packed lower triangle; factor 2 folded off-diagonal
    ws[WS_ES + EOFF_D[i] + j] = (i == j) ? Ev : 2.f * Ev;
  if (i == j) { // main-loop coefficient row, interleaved {lin_d, Q_dd..Q_d7}
    float* c0 = ws + WS_COEF + i * 48;
    int q = 0;
    #pragma unroll
    for (int d = 0; d < 8; ++d) {
      c0[q++] = pi[64 + d] * LOG2E_F;                 // lin_d
      #pragma unroll
      for (int e = d; e < 8; ++e) {
        float v = (d == e) ? -0.5f * pi[d * 8 + e] : -pi[d * 8 + e];
        c0[q++] = v * LOG2E_F;                        // Q_de
      }
    }
    c0[44] = 0.f; c0[45] = 0.f; c0[46] = 0.f; c0[47] = 0.f;
  }
  if (p == 255) ws[WS_K] = 0.5f * logdet - 32.f * LN2PI_F - 64.f * LN2_F;
}

// ---------------------------------------------------------------------------
// Kernel B: main N-loop, 2 points/thread packed in float2 lanes (v_pk_fma),
// 977 blocks (~15 waves/CU). Coefficients streamed from LDS float4 broadcast
// straight into the FMA sequence (no register array).
// Coefficient stream order per row: q=0..43 = per d {lin_d, Q_dd..Q_d7}.
// ---------------------------------------------------------------------------
__global__ __launch_bounds__(256) void gm_main(const float* __restrict__ X,
                                               const float* __restrict__ cf,
                                               float* __restrict__ partials,
                                               int N) {
  __shared__ float sc[1024];   // [0,768) coef rows; [768,928) padded E; pad
  {
    const float4* cf4 = reinterpret_cast<const float4*>(cf);
    reinterpret_cast<float4*>(sc)[threadIdx.x] = cf4[threadIdx.x];
  }

  const int t = threadIdx.x;
  const int g0i = blockIdx.x * 512 + t;       // point 0
  const int g1i = g0i + 256;                  // point 1 (coalesced)
  const bool act0 = g0i < N, act1 = g1i < N;
  const float4* Xv0 = reinterpret_cast<const float4*>(X) + (size_t)(act0 ? g0i : 0) * 2;
  const float4* Xv1 = reinterpret_cast<const float4*>(X) + (size_t)(act1 ? g1i : 0) * 2;
  float4 a0 = Xv0[0], b0 = Xv0[1];
  float4 a1 = Xv1[0], b1 = Xv1[1];
  __syncthreads();                            // staging complete

  f2 xs[8];
  xs[0] = (f2){a0.x, a1.x}; xs[1] = (f2){a0.y, a1.y};
  xs[2] = (f2){a0.z, a1.z}; xs[3] = (f2){a0.w, a1.w};
  xs[4] = (f2){b0.x, b1.x}; xs[5] = (f2){b0.y, b1.y};
  xs[6] = (f2){b0.z, b1.z}; xs[7] = (f2){b0.w, b1.w};

  // stream-consume map: for flat q = 0..43, D_OF[q] = current row d,
  // E_OF[q] = column e for quad terms, or -1 for the lin_d term.
  constexpr int D_OF[44] = {0,0,0,0,0,0,0,0,0,
                            1,1,1,1,1,1,1,1,
                            2,2,2,2,2,2,2,
                            3,3,3,3,3,3,
                            4,4,4,4,4,
                            5,5,5,5,
                            6,6,6,
                            7,7};
  constexpr int E_OF[44] = {-1,0,1,2,3,4,5,6,7,
                            -1,1,2,3,4,5,6,7,
                            -1,2,3,4,5,6,7,
                            -1,3,4,5,6,7,
                            -1,4,5,6,7,
                            -1,5,6,7,
                            -1,6,7,
                            -1,7};

  // u[i] = exp2(g_i(x))  (log2e pre-folded into coefficients)
  f2 u[16];
  #pragma unroll
  for (int i = 0; i < 16; ++i) {
    const float4* c4 = reinterpret_cast<const float4*>(sc + i * 48);
    f2 g = (f2){0.f, 0.f};
    f2 r = (f2){0.f, 0.f};
    #pragma unroll
    for (int v = 0; v < 11; ++v) {            // 11x ds_read_b128 broadcast
      float4 w = c4[v];
      #pragma unroll
      for (int k2 = 0; k2 < 4; ++k2) {
        const int q = 4 * v + k2;
        const float cc = (k2 == 0) ? w.x : (k2 == 1) ? w.y : (k2 == 2) ? w.z : w.w;
        if (E_OF[q] < 0) {                    // start of row d: flush prev row
          if (q > 0) g = __builtin_elementwise_fma(xs[D_OF[q - 1]], r, g);
          r = (f2){cc, cc};
        } else {
          r = vfma(cc, xs[E_OF[q]], r);
        }
      }
    }
    g = __builtin_elementwise_fma(xs[7], r, g);  // flush row 7
    u[i] = (f2){fexp2(g.x), fexp2(g.y)};
  }

  // pdf = sum_i u_i * (padded row_i . u)   [diag=E'_ii, off=2E'_ij, pads=0]
  constexpr int EOFF[16]  = {0,4,8,12,16,24,32,40,48,60,72,84,96,112,128,144};
  constexpr int ELEN4[16] = {1,1,1,1,2,2,2,2,3,3,3,3,4,4,4,4};
  const float4* es4 = reinterpret_cast<const float4*>(sc + 768);
  f2 pdf = (f2){0.f, 0.f};
  #pragma unroll
  for (int i = 0; i < 16; ++i) {
    f2 s = (f2){0.f, 0.f};
    #pragma unroll
    for (int q4 = 0; q4 < ELEN4[i]; ++q4) {   // ds_read_b128 per 4 E entries
      float4 ev = es4[EOFF[i] / 4 + q4];
      const int j = q4 * 4;
      s = vfma(ev.x, u[j + 0], s);
      s = vfma(ev.y, u[j + 1], s);
      s = vfma(ev.z, u[j + 2], s);
      s = vfma(ev.w, u[j + 3], s);
    }
    pdf = __builtin_elementwise_fma(u[i], s, pdf);
  }
  float lsum = 0.f;
  if (act0) lsum += flog2(pdf.x);
  if (act1) lsum += flog2(pdf.y);

  // deterministic block reduction of sum(log2 pdf)
  #pragma unroll
  for (int off = 32; off > 0; off >>= 1) lsum += __shfl_down(lsum, off, 64);
  __shared__ float wsum[4];
  int lane = threadIdx.x & 63, wid = threadIdx.x >> 6;
  if (lane == 0) wsum[wid] = lsum;
  __syncthreads();
  if (threadIdx.x == 0)
    partials[blockIdx.x] = (wsum[0] + wsum[1]) + (wsum[2] + wsum[3]);
}

// ---------------------------------------------------------------------------
// Kernel C: deterministic final reduction (fixed-order strided + tree)
// ---------------------------------------------------------------------------
__global__ __launch_bounds__(256) void gm_final(const float* __restrict__ ws,
                                                float* __restrict__ out,
                                                int nb, float invN) {
  const float* partials = ws + WS_PART;
  float s = 0.f;
  for (int t = threadIdx.x; t < nb; t += 256) s += partials[t];
  #pragma unroll
  for (int off = 32; off > 0; off >>= 1) s += __shfl_down(s, off, 64);
  __shared__ float wsum[4];
  int lane = threadIdx.x & 63, wid = threadIdx.x >> 6;
  if (lane == 0) wsum[wid] = s;
  __syncthreads();
  if (threadIdx.x == 0) {
    float tot = (wsum[0] + wsum[1]) + (wsum[2] + wsum[3]);
    // mean(ln pdf_true) + ln z_last = ln2 * mean(log2 pdf_scaled) + Kconst
    out[0] = tot * LN2_F * invN + ws[WS_K];
  }
}

extern "C" void kernel_launch(void* const* d_in, const int* in_sizes, int n_in,
                              void* d_out, int out_size, void* d_ws, size_t ws_size,
                              hipStream_t stream) {
  const float* X = (const float*)d_in[0];
  const float* mu = (const float*)d_in[1];
  const float* L = (const float*)d_in[2];
  const float* wts = (const float*)d_in[3];
  // d_in[4] ("it") is unused by the reference math.
  float* ws = (float*)d_ws;
  float* out = (float*)d_out;
  int N = in_sizes[0] / 8;
  int nb = (N + 511) / 512;              // 2 points per thread, 256 threads
  gm_setup<<<1, 256, 0, stream>>>(mu, L, wts, ws);
  gm_main<<<nb, 256, 0, stream>>>(X, ws, ws + WS_PART, N);
  gm_final<<<1, 256, 0, stream>>>(ws, out, nb, 1.0f / (float)N);
}

// Round 9
// 24.250 us; speedup vs baseline: 1.0740x; 1.0740x over previous
//
#include <hip/hip_runtime.h>
#include <math.h>

// ---------------------------------------------------------------------------
// N-pair Gaussian mixture log-likelihood, factorized form:
//   arg_ij(x) = g_i(x) + g_j(x) + c_ij,  g_i(x) = -0.5 x'prec_i x + x'rhs_i
//   pdf(x)    = u' E u,  u_i = exp(g_i(x)),  E_ij = exp(c_ij + 64 ln2)  [scaled]
//   out       = mean_n( log pdf_n ) + log z_last   (scale folded into Kconst)
// Main kernel: 4 points/thread as TWO float2 packs -> v_pk_fma_f32 with the
// LDS-read amortization of 4pt/thread. No atomics -> deterministic.
// ---------------------------------------------------------------------------

#define LOG2E_F 1.4426950408889634f
#define LN2_F   0.6931471805599453f
#define LN2PI_F 1.8378770664093453f   // ln(2*pi)

// ws layout (float offsets). Staged region = [0,1024) = 256 float4.
#define WS_COEF 0      // 16 rows * 48: per d {lin_d, Q_dd..Q_d7} *log2e; 44 used
#define WS_ES   768    // 160: packed lower-tri E rows, each padded to 16B
#define WS_K    1024   // Kconst = log z_last - 64 ln2  (outside staged region)
#define WS_PART 1088   // per-block partial sums

typedef float f2 __attribute__((ext_vector_type(2)));

// Padded-packed E row offsets (floats)
__device__ const int EOFF_D[16] = {0,4,8,12,16,24,32,40,48,60,72,84,96,112,128,144};

__device__ __forceinline__ float fexp2(float x) {
#if __has_builtin(__builtin_amdgcn_exp2f)
  return __builtin_amdgcn_exp2f(x);
#else
  return exp2f(x);
#endif
}
__device__ __forceinline__ float flog2(float x) {
#if __has_builtin(__builtin_amdgcn_logf)
  return __builtin_amdgcn_logf(x);
#else
  return log2f(x);
#endif
}
__device__ __forceinline__ f2 vfma(float c, f2 x, f2 a) {   // v_pk_fma_f32
  return __builtin_elementwise_fma((f2){c, c}, x, a);
}

// Cholesky: A = C C^T (lower). Only lower triangle of A read. Fully unrolled.
__device__ __forceinline__ void chol8(const float (*A)[8], float (*C)[8]) {
  #pragma unroll
  for (int d = 0; d < 8; ++d) {
    float s = A[d][d];
    #pragma unroll
    for (int m = 0; m < 8; ++m) if (m < d) s -= C[d][m] * C[d][m];
    float cd = sqrtf(s);
    C[d][d] = cd;
    float inv = 1.f / cd;
    #pragma unroll
    for (int e = 0; e < 8; ++e) if (e > d) {
      float t = A[e][d];
      #pragma unroll
      for (int m = 0; m < 8; ++m) if (m < d) t -= C[e][m] * C[d][m];
      C[e][d] = t * inv;
    }
  }
}

// ---------------------------------------------------------------------------
// Kernel A: all setup in one block (unchanged; correctness-proven).
// ---------------------------------------------------------------------------
__global__ __launch_bounds__(256) void gm_setup(const float* __restrict__ mu,
                                                const float* __restrict__ L,
                                                const float* __restrict__ wts,
                                                float* __restrict__ ws) {
  __shared__ float sp[16][72];   // prec[64] + rhs[8] per component
  int tid = threadIdx.x;
  ws[768 + tid] = 0.f;           // zero [768,1024): E pads + tail
  if (tid < 16) {
    int k = tid;
    float Lt[8][8];
    #pragma unroll
    for (int d = 0; d < 8; ++d)
      #pragma unroll
      for (int e = 0; e < 8; ++e)
        Lt[d][e] = (e <= d) ? L[k * 64 + d * 8 + e] : 0.f;
    float A[8][8];
    #pragma unroll
    for (int d = 0; d < 8; ++d)
      #pragma unroll
      for (int e = 0; e <= d; ++e) {
        float s = (d == e) ? 1.f : 0.f;
        #pragma unroll
        for (int m = 0; m < 8; ++m) s += Lt[d][m] * Lt[e][m];
        A[d][e] = s;
        A[e][d] = s;
      }
    float C[8][8];
    chol8(A, C);
    float Ci[8][8];
    #pragma unroll
    for (int d = 0; d < 8; ++d) Ci[d][d] = 1.f / C[d][d];
    #pragma unroll
    for (int e = 0; e < 8; ++e)
      #pragma unroll
      for (int d = 0; d < 8; ++d) if (d > e) {
        float s = 0.f;
        #pragma unroll
        for (int m = 0; m < 8; ++m) if (m >= e && m < d) s += C[d][m] * Ci[m][e];
        Ci[d][e] = -s * Ci[d][d];
      }
    #pragma unroll
    for (int a = 0; a < 8; ++a)
      #pragma unroll
      for (int b = 0; b < 8; ++b) {
        float s = 0.f;
        #pragma unroll
        for (int m = 0; m < 8; ++m) if (m >= a && m >= b) s += Ci[m][a] * Ci[m][b];
        sp[k][a * 8 + b] = s;
      }
    #pragma unroll
    for (int d = 0; d < 8; ++d) {
      float s = 0.f;
      #pragma unroll
      for (int e = 0; e < 8; ++e) s += sp[k][d * 8 + e] * mu[k * 8 + e];
      sp[k][64 + d] = s;
    }
  }
  __syncthreads();

  int p = tid;
  int i = p >> 4, j = p & 15;
  const float* pi = sp[i];
  const float* pj = sp[j];
  float P[8][8], rp[8];
  #pragma unroll
  for (int d = 0; d < 8; ++d) {
    #pragma unroll
    for (int e = 0; e < 8; ++e) P[d][e] = pi[d * 8 + e] + pj[d * 8 + e];
    rp[d] = pi[64 + d] + pj[64 + d];
  }
  float U[8][8];
  chol8(P, U);
  float logdet = 0.f;
  #pragma unroll
  for (int d = 0; d < 8; ++d) logdet += logf(U[d][d]);
  logdet *= 2.f;
  float zf[8];
  #pragma unroll
  for (int d = 0; d < 8; ++d) {
    float s = rp[d];
    #pragma unroll
    for (int m = 0; m < 8; ++m) if (m < d) s -= U[d][m] * zf[m];
    zf[d] = s / U[d][d];
  }
  float y[8];
  #pragma unroll
  for (int dd = 7; dd >= 0; --dd) {
    float s = zf[dd];
    #pragma unroll
    for (int m = 0; m < 8; ++m) if (m > dd) s -= U[m][dd] * y[m];
    y[dd] = s / U[dd][dd];
  }
  float muPmu = 0.f;
  #pragma unroll
  for (int d = 0; d < 8; ++d) muPmu += rp[d] * y[d];
  float c = -0.5f * muPmu + 0.5f * logdet - 32.f * LN2PI_F
          + logf(wts[i]) + logf(wts[j]) + 64.f * LN2_F;
  float Ev = expf(c);
  if (j <= i)   // padded-packed lower triangle; factor 2 folded off-diagonal
    ws[WS_ES + EOFF_D[i] + j] = (i == j) ? Ev : 2.f * Ev;
  if (i == j) { // main-loop coefficient row, interleaved {lin_d, Q_dd..Q_d7}
    float* c0 = ws + WS_COEF + i * 48;
    int q = 0;
    #pragma unroll
    for (int d = 0; d < 8; ++d) {
      c0[q++] = pi[64 + d] * LOG2E_F;                 // lin_d
      #pragma unroll
      for (int e = d; e < 8; ++e) {
        float v = (d == e) ? -0.5f * pi[d * 8 + e] : -pi[d * 8 + e];
        c0[q++] = v * LOG2E_F;                        // Q_de
      }
    }
    c0[44] = 0.f; c0[45] = 0.f; c0[46] = 0.f; c0[47] = 0.f;
  }
  if (p == 255) ws[WS_K] = 0.5f * logdet - 32.f * LN2PI_F - 64.f * LN2_F;
}

// ---------------------------------------------------------------------------
// Kernel B: main N-loop, 4 points/thread as TWO f2 packs (v_pk_fma_f32).
// 489 blocks. 51 ds_read_b128 broadcasts per point-set, ~1840 VALU insts
// per 4 points (half of the scalar-FMA version).
// Coefficient stream order per row: q=0..43 = per d {lin_d, Q_dd..Q_d7}.
// ---------------------------------------------------------------------------
__global__ __launch_bounds__(256) void gm_main(const float* __restrict__ X,
                                               const float* __restrict__ cf,
                                               float* __restrict__ partials,
                                               int N) {
  __shared__ float sc[1024];   // [0,768) coef rows; [768,928) padded E; pad
  {
    const float4* cf4 = reinterpret_cast<const float4*>(cf);
    reinterpret_cast<float4*>(sc)[threadIdx.x] = cf4[threadIdx.x];
  }

  const int t = threadIdx.x;
  const int base = blockIdx.x * 1024 + t;
  bool act[4];
  float4 xa[4], xb[4];
  #pragma unroll
  for (int g = 0; g < 4; ++g) {
    int gid = base + g * 256;
    act[g] = gid < N;
    const float4* Xv =
        reinterpret_cast<const float4*>(X) + (size_t)(act[g] ? gid : 0) * 2;
    xa[g] = Xv[0];
    xb[g] = Xv[1];
  }
  __syncthreads();                            // staging complete

  // two f2 packs: lanes {pt0,pt1} and {pt2,pt3}
  f2 xs01[8], xs23[8];
  xs01[0] = (f2){xa[0].x, xa[1].x}; xs23[0] = (f2){xa[2].x, xa[3].x};
  xs01[1] = (f2){xa[0].y, xa[1].y}; xs23[1] = (f2){xa[2].y, xa[3].y};
  xs01[2] = (f2){xa[0].z, xa[1].z}; xs23[2] = (f2){xa[2].z, xa[3].z};
  xs01[3] = (f2){xa[0].w, xa[1].w}; xs23[3] = (f2){xa[2].w, xa[3].w};
  xs01[4] = (f2){xb[0].x, xb[1].x}; xs23[4] = (f2){xb[2].x, xb[3].x};
  xs01[5] = (f2){xb[0].y, xb[1].y}; xs23[5] = (f2){xb[2].y, xb[3].y};
  xs01[6] = (f2){xb[0].z, xb[1].z}; xs23[6] = (f2){xb[2].z, xb[3].z};
  xs01[7] = (f2){xb[0].w, xb[1].w}; xs23[7] = (f2){xb[2].w, xb[3].w};

  // stream-consume map: for flat q = 0..43, D_OF[q] = current row d,
  // E_OF[q] = column e for quad terms, or -1 for the lin_d term.
  constexpr int D_OF[44] = {0,0,0,0,0,0,0,0,0,
                            1,1,1,1,1,1,1,1,
                            2,2,2,2,2,2,2,
                            3,3,3,3,3,3,
                            4,4,4,4,4,
                            5,5,5,5,
                            6,6,6,
                            7,7};
  constexpr int E_OF[44] = {-1,0,1,2,3,4,5,6,7,
                            -1,1,2,3,4,5,6,7,
                            -1,2,3,4,5,6,7,
                            -1,3,4,5,6,7,
                            -1,4,5,6,7,
                            -1,5,6,7,
                            -1,6,7,
                            -1,7};

  // u[i] = exp2(g_i(x))  (log2e pre-folded into coefficients)
  f2 u01[16], u23[16];
  #pragma unroll
  for (int i = 0; i < 16; ++i) {
    const float4* c4 = reinterpret_cast<const float4*>(sc + i * 48);
    f2 g01 = (f2){0.f, 0.f}, g23 = (f2){0.f, 0.f};
    f2 r01 = (f2){0.f, 0.f}, r23 = (f2){0.f, 0.f};
    #pragma unroll
    for (int v = 0; v < 11; ++v) {            // 11x ds_read_b128 broadcast
      float4 w = c4[v];
      #pragma unroll
      for (int k2 = 0; k2 < 4; ++k2) {
        const int q = 4 * v + k2;
        const float cc = (k2 == 0) ? w.x : (k2 == 1) ? w.y : (k2 == 2) ? w.z : w.w;
        if (E_OF[q] < 0) {                    // start of row d: flush prev row
          if (q > 0) {
            g01 = __builtin_elementwise_fma(xs01[D_OF[q - 1]], r01, g01);
            g23 = __builtin_elementwise_fma(xs23[D_OF[q - 1]], r23, g23);
          }
          r01 = (f2){cc, cc};
          r23 = (f2){cc, cc};
        } else {
          r01 = vfma(cc, xs01[E_OF[q]], r01);
          r23 = vfma(cc, xs23[E_OF[q]], r23);
        }
      }
    }
    g01 = __builtin_elementwise_fma(xs01[7], r01, g01);  // flush row 7
    g23 = __builtin_elementwise_fma(xs23[7], r23, g23);
    u01[i] = (f2){fexp2(g01.x), fexp2(g01.y)};
    u23[i] = (f2){fexp2(g23.x), fexp2(g23.y)};
  }

  // pdf = sum_i u_i * (padded row_i . u)   [diag=E'_ii, off=2E'_ij, pads=0]
  constexpr int EOFF[16]  = {0,4,8,12,16,24,32,40,48,60,72,84,96,112,128,144};
  constexpr int ELEN4[16] = {1,1,1,1,2,2,2,2,3,3,3,3,4,4,4,4};
  const float4* es4 = reinterpret_cast<const float4*>(sc + 768);
  f2 pdf01 = (f2){0.f, 0.f}, pdf23 = (f2){0.f, 0.f};
  #pragma unroll
  for (int i = 0; i < 16; ++i) {
    f2 s01 = (f2){0.f, 0.f}, s23 = (f2){0.f, 0.f};
    #pragma unroll
    for (int q4 = 0; q4 < ELEN4[i]; ++q4) {   // ds_read_b128 per 4 E entries
      float4 ev = es4[EOFF[i] / 4 + q4];
      const int j = q4 * 4;
      s01 = vfma(ev.x, u01[j + 0], s01); s23 = vfma(ev.x, u23[j + 0], s23);
      s01 = vfma(ev.y, u01[j + 1], s01); s23 = vfma(ev.y, u23[j + 1], s23);
      s01 = vfma(ev.z, u01[j + 2], s01); s23 = vfma(ev.z, u23[j + 2], s23);
      s01 = vfma(ev.w, u01[j + 3], s01); s23 = vfma(ev.w, u23[j + 3], s23);
    }
    pdf01 = __builtin_elementwise_fma(u01[i], s01, pdf01);
    pdf23 = __builtin_elementwise_fma(u23[i], s23, pdf23);
  }
  float lsum = 0.f;
  if (act[0]) lsum += flog2(pdf01.x);
  if (act[1]) lsum += flog2(pdf01.y);
  if (act[2]) lsum += flog2(pdf23.x);
  if (act[3]) lsum += flog2(pdf23.y);

  // deterministic block reduction of sum(log2 pdf)
  #pragma unroll
  for (int off = 32; off > 0; off >>= 1) lsum += __shfl_down(lsum, off, 64);
  __shared__ float wsum[4];
  int lane = threadIdx.x & 63, wid = threadIdx.x >> 6;
  if (lane == 0) wsum[wid] = lsum;
  __syncthreads();
  if (threadIdx.x == 0)
    partials[blockIdx.x] = (wsum[0] + wsum[1]) + (wsum[2] + wsum[3]);
}

// ---------------------------------------------------------------------------
// Kernel C: deterministic final reduction (fixed-order strided + tree)
// ---------------------------------------------------------------------------
__global__ __launch_bounds__(256) void gm_final(const float* __restrict__ ws,
                                                float* __restrict__ out,
                                                int nb, float invN) {
  const float* partials = ws + WS_PART;
  float s = 0.f;
  for (int t = threadIdx.x; t < nb; t += 256) s += partials[t];
  #pragma unroll
  for (int off = 32; off > 0; off >>= 1) s += __shfl_down(s, off, 64);
  __shared__ float wsum[4];
  int lane = threadIdx.x & 63, wid = threadIdx.x >> 6;
  if (lane == 0) wsum[wid] = s;
  __syncthreads();
  if (threadIdx.x == 0) {
    float tot = (wsum[0] + wsum[1]) + (wsum[2] + wsum[3]);
    // mean(ln pdf_true) + ln z_last = ln2 * mean(log2 pdf_scaled) + Kconst
    out[0] = tot * LN2_F * invN + ws[WS_K];
  }
}

extern "C" void kernel_launch(void* const* d_in, const int* in_sizes, int n_in,
                              void* d_out, int out_size, void* d_ws, size_t ws_size,
                              hipStream_t stream) {
  const float* X = (const float*)d_in[0];
  const float* mu = (const float*)d_in[1];
  const float* L = (const float*)d_in[2];
  const float* wts = (const float*)d_in[3];
  // d_in[4] ("it") is unused by the reference math.
  float* ws = (float*)d_ws;
  float* out = (float*)d_out;
  int N = in_sizes[0] / 8;
  int nb = (N + 1023) / 1024;            // 4 points per thread, 256 threads
  gm_setup<<<1, 256, 0, stream>>>(mu, L, wts, ws);
  gm_main<<<nb, 256, 0, stream>>>(X, ws, ws + WS_PART, N);
  gm_final<<<1, 256, 0, stream>>>(ws, out, nb, 1.0f / (float)N);
}